// Round 3
// baseline (842.313 us; speedup 1.0000x reference)
//
#include <hip/hip_runtime.h>
#include <math.h>

#define N_NODES 100000
#define N_EDGES 1600000
#define HID 48
#define ALPHA 0.1f

// 3 src tiles; tile = src / 33334. Key = tile*TSTRIDE + dst (tile-major CSR).
#define TSTRIDE 100352              // 2048*49, scan-friendly
#define NKEYS   (3 * TSTRIDE)       // 301056 = 2048*147
#define SCAN_BLOCKS 147

typedef unsigned short u16;

__device__ __forceinline__ float bf2f(u16 u) {
    return __uint_as_float(((unsigned int)u) << 16);
}
__device__ __forceinline__ u16 f2bf(float f) {
    unsigned int b = __float_as_uint(f);
    b += 0x7fff + ((b >> 16) & 1);   // round-to-nearest-even
    return (u16)(b >> 16);
}

// ---------------- lin0: h0 = relu(x @ W0 + b0); writes f32 x0 AND bf16 h0 ----------------
__global__ __launch_bounds__(256) void lin0_k(const float* __restrict__ x, const float* __restrict__ W0,
                                              const float* __restrict__ b0, float* __restrict__ x0f,
                                              u16* __restrict__ h0) {
    int t = blockIdx.x * 256 + threadIdx.x;
    if (t >= N_NODES * HID) return;
    int node = t / HID, f = t % HID;
    float v = b0[f]
            + x[node * 3 + 0] * W0[0 * HID + f]
            + x[node * 3 + 1] * W0[1 * HID + f]
            + x[node * 3 + 2] * W0[2 * HID + f];
    v = v > 0.f ? v : 0.f;
    x0f[t] = v;
    h0[t] = f2bf(v);
}

// ---------------- CSR build over keys (src_tile, dst) ----------------
__global__ __launch_bounds__(256) void count_k(const int* __restrict__ src, const int* __restrict__ dst,
                                               int* __restrict__ deg) {
    int e = blockIdx.x * 256 + threadIdx.x;
    if (e < N_EDGES) {
        int s = src[e], d = dst[e];
        int key = (s / 33334) * TSTRIDE + d;
        atomicAdd(&deg[key], 1);
    }
}

__global__ __launch_bounds__(256) void scan1_k(const int* __restrict__ deg, int* __restrict__ rowptr,
                                               int* __restrict__ partial) {
    __shared__ int sums[256];
    int tid = threadIdx.x;
    int base = blockIdx.x * 2048 + tid * 8;
    int v[8]; int s = 0;
#pragma unroll
    for (int j = 0; j < 8; j++) { int idx = base + j; v[j] = (idx < NKEYS) ? deg[idx] : 0; s += v[j]; }
    sums[tid] = s; __syncthreads();
    for (int off = 1; off < 256; off <<= 1) {
        int t = (tid >= off) ? sums[tid - off] : 0;
        __syncthreads();
        sums[tid] += t;
        __syncthreads();
    }
    if (tid == 255) partial[blockIdx.x] = sums[255];
    int run = (tid > 0) ? sums[tid - 1] : 0;
#pragma unroll
    for (int j = 0; j < 8; j++) { int idx = base + j; if (idx < NKEYS) rowptr[idx] = run; run += v[j]; }
}

__global__ void scan2_k(int* __restrict__ partial, int* __restrict__ rowptr, int nblk) {
    if (threadIdx.x == 0 && blockIdx.x == 0) {
        int acc = 0;
        for (int i = 0; i < nblk; i++) { int t = partial[i]; partial[i] = acc; acc += t; }
        rowptr[NKEYS] = acc;
    }
}

__global__ __launch_bounds__(256) void scan3_k(int* __restrict__ rowptr, int* __restrict__ cursor,
                                               const int* __restrict__ partial) {
    int tid = threadIdx.x;
    int base = blockIdx.x * 2048 + tid * 8;
    int add = partial[blockIdx.x];
#pragma unroll
    for (int j = 0; j < 8; j++) {
        int idx = base + j;
        if (idx < NKEYS) { int v = rowptr[idx] + add; rowptr[idx] = v; cursor[idx] = v; }
    }
}

__global__ __launch_bounds__(256) void bucket_k(const int* __restrict__ src, const int* __restrict__ dst,
                                                int* __restrict__ cursor, int* __restrict__ ssrc) {
    int e = blockIdx.x * 256 + threadIdx.x;
    if (e < N_EDGES) {
        int s = src[e], d = dst[e];
        int key = (s / 33334) * TSTRIDE + d;
        int p = atomicAdd(&cursor[key], 1);
        ssrc[p] = s;
    }
}

// ---------------- tiled aggregation passes ----------------
// one wave per node; lanes 0..47 = features. Grid = 25000 blocks x 256 = exactly 100000 waves.
// MODE 0: acc = sum(tile)        (first tile)
// MODE 1: acc += sum(tile)       (middle tile)
// MODE 2: fused: t = (1-a)*(acc+sum) + a*x0; h_out = relu((1-b)*t + b*(t@W))   (last tile)
template<int MODE>
__global__ __launch_bounds__(256) void agg_k(const u16* __restrict__ h_in, float* __restrict__ acc,
                                             const int* __restrict__ rowptr, const int* __restrict__ ssrc,
                                             int tile,
                                             const float* __restrict__ x0, const float* __restrict__ W,
                                             float beta, u16* __restrict__ h_out) {
    __shared__ float tbuf[4][48];
    int tid = threadIdx.x, wave = tid >> 6, lane = tid & 63;
    int node = blockIdx.x * 4 + wave;
    int f = lane < 48 ? lane : 0;
    int base = tile * TSTRIDE + node;
    int e0 = rowptr[base], e1 = rowptr[base + 1];
    float s = 0.f;
    int e = e0;
    for (; e + 4 <= e1; e += 4) {
        int s0 = ssrc[e + 0], s1 = ssrc[e + 1], s2 = ssrc[e + 2], s3 = ssrc[e + 3];
        float a0 = bf2f(h_in[s0 * 48 + f]);
        float a1 = bf2f(h_in[s1 * 48 + f]);
        float a2 = bf2f(h_in[s2 * 48 + f]);
        float a3 = bf2f(h_in[s3 * 48 + f]);
        s += (a0 + a1) + (a2 + a3);
    }
    for (; e < e1; e++) s += bf2f(h_in[ssrc[e] * 48 + f]);

    if constexpr (MODE == 0) {
        if (lane < 48) acc[node * 48 + lane] = s;
    } else if constexpr (MODE == 1) {
        if (lane < 48) acc[node * 48 + lane] += s;
    } else {
        float t = (1.f - ALPHA) * (acc[node * 48 + f] + s) + ALPHA * x0[node * 48 + f];
        if (lane < 48) tbuf[wave][lane] = t;
        // wave-private LDS slice: no block barrier needed (single instruction stream per wave)
        if (lane < 48) {
            const float4* t4 = (const float4*)tbuf[wave];
            float acc2 = 0.f;
#pragma unroll
            for (int k4 = 0; k4 < 12; k4++) {
                float4 tv = t4[k4];
                acc2 += tv.x * W[(4 * k4 + 0) * 48 + lane] + tv.y * W[(4 * k4 + 1) * 48 + lane]
                      + tv.z * W[(4 * k4 + 2) * 48 + lane] + tv.w * W[(4 * k4 + 3) * 48 + lane];
            }
            float o = (1.f - beta) * t + beta * acc2;
            h_out[node * 48 + lane] = f2bf(o > 0.f ? o : 0.f);
        }
    }
}

// ---------------- final: out = log_softmax(h @ W1 + b1) ----------------
__global__ __launch_bounds__(256) void final_k(const u16* __restrict__ h, const float* __restrict__ W1,
                                               const float* __restrict__ b1, float* __restrict__ out) {
    __shared__ float tbuf[4][48];
    int tid = threadIdx.x, wave = tid >> 6, lane = tid & 63;
    int node = blockIdx.x * 4 + wave;
    int f = lane < 48 ? lane : 0;
    if (lane < 48) tbuf[wave][lane] = bf2f(h[node * 48 + lane]);
    float v = -INFINITY;
    {
        const float4* t4 = (const float4*)tbuf[wave];
        float s = b1[f];
#pragma unroll
        for (int k4 = 0; k4 < 12; k4++) {
            float4 tv = t4[k4];
            s += tv.x * W1[(4 * k4 + 0) * 48 + f] + tv.y * W1[(4 * k4 + 1) * 48 + f]
               + tv.z * W1[(4 * k4 + 2) * 48 + f] + tv.w * W1[(4 * k4 + 3) * 48 + f];
        }
        if (lane < 48) v = s;
    }
    float m = v;
    for (int off = 32; off >= 1; off >>= 1) m = fmaxf(m, __shfl_xor(m, off));
    float ex = (lane < 48) ? expf(v - m) : 0.f;
    float sum = ex;
    for (int off = 32; off >= 1; off >>= 1) sum += __shfl_xor(sum, off);
    if (lane < 48) out[node * 48 + lane] = v - m - logf(sum);
}

extern "C" void kernel_launch(void* const* d_in, const int* in_sizes, int n_in,
                              void* d_out, int out_size, void* d_ws, size_t ws_size,
                              hipStream_t stream) {
    const float* x     = (const float*)d_in[0];
    const int*   ei    = (const int*)d_in[1];
    const float* W0    = (const float*)d_in[2];
    const float* b0    = (const float*)d_in[3];
    const float* convW = (const float*)d_in[4];
    const float* W1    = (const float*)d_in[5];
    const float* b1    = (const float*)d_in[6];
    float* out = (float*)d_out;
    const int* src = ei;            // edge_index[0]
    const int* dst = ei + N_EDGES;  // edge_index[1]

    char* ws = (char*)d_ws;
    size_t off = 0;
    float* x0   = (float*)(ws + off); off += (size_t)N_NODES * 48 * 4;   // 19.2 MB f32 residual
    float* accb = (float*)(ws + off); off += (size_t)N_NODES * 48 * 4;   // 19.2 MB f32 partial agg
    u16* hA     = (u16*)(ws + off);   off += (size_t)N_NODES * 48 * 2;   // 9.6 MB bf16
    u16* hB     = (u16*)(ws + off);   off += (size_t)N_NODES * 48 * 2;   // 9.6 MB bf16
    int* ssrc   = (int*)(ws + off);   off += (size_t)N_EDGES * 4;        // 6.4 MB
    int* rowptr = (int*)(ws + off);   off += (size_t)(NKEYS + 1) * 4;    // 1.2 MB
    off = (off + 255) & ~(size_t)255;
    int* cursor = (int*)(ws + off);   off += (size_t)NKEYS * 4;
    off = (off + 255) & ~(size_t)255;
    int* deg    = (int*)(ws + off);   off += (size_t)NKEYS * 4;
    off = (off + 255) & ~(size_t)255;
    int* partial = (int*)(ws + off);  off += (size_t)SCAN_BLOCKS * 4;

    hipMemsetAsync(deg, 0, (size_t)NKEYS * 4, stream);

    lin0_k<<<18750, 256, 0, stream>>>(x, W0, b0, x0, hA);
    count_k<<<6250, 256, 0, stream>>>(src, dst, deg);
    scan1_k<<<SCAN_BLOCKS, 256, 0, stream>>>(deg, rowptr, partial);
    scan2_k<<<1, 64, 0, stream>>>(partial, rowptr, SCAN_BLOCKS);
    scan3_k<<<SCAN_BLOCKS, 256, 0, stream>>>(rowptr, cursor, partial);
    bucket_k<<<6250, 256, 0, stream>>>(src, dst, cursor, ssrc);

    const float betas[4] = { logf(1.5f), logf(1.25f), logf(7.f / 6.f), logf(1.125f) };

    u16* hin = hA; u16* hout = hB;
    for (int l = 0; l < 4; l++) {
        const float* W = convW + l * 2304;
        agg_k<0><<<25000, 256, 0, stream>>>(hin, accb, rowptr, ssrc, 0, x0, W, betas[l], hout);
        agg_k<1><<<25000, 256, 0, stream>>>(hin, accb, rowptr, ssrc, 1, x0, W, betas[l], hout);
        agg_k<2><<<25000, 256, 0, stream>>>(hin, accb, rowptr, ssrc, 2, x0, W, betas[l], hout);
        u16* tmp = hin; hin = hout; hout = tmp;
    }
    final_k<<<25000, 256, 0, stream>>>(hin, W1, b1, out);
}